// Round 2
// baseline (594.743 us; speedup 1.0000x reference)
//
#include <hip/hip_runtime.h>

typedef unsigned short u16;
typedef __attribute__((ext_vector_type(8))) short bf8v;   // 8 bf16 = 4 VGPRs
typedef __attribute__((ext_vector_type(4))) float f4v;

#define DEV static __device__ __forceinline__

DEV float bf2f(u16 u){ unsigned x = ((unsigned)u) << 16; float f; __builtin_memcpy(&f, &x, 4); return f; }
DEV u16 f2bf(float f){ unsigned x; __builtin_memcpy(&x, &f, 4); x += 0x7fff + ((x >> 16) & 1); return (u16)(x >> 16); }

DEV void async16(const void* g, void* l){
  __builtin_amdgcn_global_load_lds((const __attribute__((address_space(1))) unsigned*)g,
                                   (__attribute__((address_space(3))) unsigned*)l, 16, 0, 0);
}

// ---------------------------------------------------------------------------
// fp32 -> bf16 conversion, 4 elements/thread, exact-size grids.
// ---------------------------------------------------------------------------
__global__ __launch_bounds__(256) void f2b_k(const float* __restrict__ src,
                                             u16* __restrict__ dst)
{
  const long i = ((long)blockIdx.x * 256 + threadIdx.x) * 4;
  const float4 v = *(const float4*)(src + i);
  ushort4 o;
  o.x = f2bf(v.x); o.y = f2bf(v.y); o.z = f2bf(v.z); o.w = f2bf(v.w);
  *(ushort4*)(dst + i) = o;
}

// ---------------------------------------------------------------------------
// GEMM: C[M,N] = A[M,K] * B[N,K]^T, bf16 in, fp32 accum.
// M=4096, N=2048, K=2048. 128x128 tile, BK=32, 4 waves (2x2 of 64x64).
// mode 0: C bf16 row-major [M,N].
// mode 1: V-transpose epilogue -> bf16 [bh, d, s].
// mode 2: Cf fp32 row-major [M,N] (final output).
// ---------------------------------------------------------------------------
constexpr int MDIM = 4096, NDIM = 2048, KDIM = 2048;

__global__ __launch_bounds__(256) void gemm_bt(const u16* __restrict__ A,
                                               const u16* __restrict__ B,
                                               u16* __restrict__ C,
                                               float* __restrict__ Cf, int mode)
{
  __shared__ __align__(16) u16 As[128 * 32];   // 8 KB
  __shared__ __align__(16) u16 Bs[128 * 32];   // 8 KB
  const int tid = threadIdx.x;
  const int w = tid >> 6, lane = tid & 63;
  const int ln = lane & 15, quad = lane >> 4;
  const int wm = (w >> 1) << 6, wn = (w & 1) << 6;
  const long m0 = (long)blockIdx.y << 7, n0 = (long)blockIdx.x << 7;

  f4v acc[4][4] = {};

  // staging: chunk c in [0,512): row=c>>2 (0..127), dd=c&3; LDS byte off = c*16
  const int c0 = tid, c1 = 256 + tid;
  const u16* ga0 = A + (m0 + (c0 >> 2)) * KDIM + (c0 & 3) * 8;
  const u16* ga1 = A + (m0 + (c1 >> 2)) * KDIM + (c1 & 3) * 8;
  const u16* gb0 = B + (n0 + (c0 >> 2)) * KDIM + (c0 & 3) * 8;
  const u16* gb1 = B + (n0 + (c1 >> 2)) * KDIM + (c1 & 3) * 8;
  char* lA0 = (char*)As + w * 1024;          // wave-uniform base; HW adds lane*16
  char* lA1 = (char*)As + 4096 + w * 1024;
  char* lB0 = (char*)Bs + w * 1024;
  char* lB1 = (char*)Bs + 4096 + w * 1024;

  for (int k0 = 0; k0 < KDIM; k0 += 32) {
    __syncthreads();
    async16(ga0 + k0, lA0);
    async16(ga1 + k0, lA1);
    async16(gb0 + k0, lB0);
    async16(gb1 + k0, lB1);
    __syncthreads();
    bf8v a[4], b[4];
#pragma unroll
    for (int i = 0; i < 4; i++) a[i] = *(const bf8v*)&As[(wm + i * 16 + ln) * 32 + quad * 8];
#pragma unroll
    for (int j = 0; j < 4; j++) b[j] = *(const bf8v*)&Bs[(wn + j * 16 + ln) * 32 + quad * 8];
#pragma unroll
    for (int i = 0; i < 4; i++)
#pragma unroll
      for (int j = 0; j < 4; j++)
        acc[i][j] = __builtin_amdgcn_mfma_f32_16x16x32_bf16(a[i], b[j], acc[i][j], 0, 0, 0);
  }

  // epilogue: D row = quad*4+reg (m), col = ln (n)  [measured m89/m91 layout]
#pragma unroll
  for (int i = 0; i < 4; i++) {
    const long mrow = m0 + wm + i * 16 + quad * 4;
#pragma unroll
    for (int j = 0; j < 4; j++) {
      const long ncol = n0 + wn + j * 16 + ln;
#pragma unroll
      for (int r = 0; r < 4; r++) {
        const float fv = acc[i][j][r];
        const long m = mrow + r;
        if (mode == 0) {
          C[m * NDIM + ncol] = f2bf(fv);
        } else if (mode == 2) {
          Cf[m * NDIM + ncol] = fv;
        } else {
          // m = b*2048 + s ; ncol = h*128 + d  ->  C[(b*16+h)*128 + d][s]
          const long s = m & 2047, bb = m >> 11;
          const long hh = ncol >> 7, dc = ncol & 127;
          C[((bb * 16 + hh) * 128 + dc) * 2048 + s] = f2bf(fv);
        }
      }
    }
  }
}

// ---------------------------------------------------------------------------
// RoPE in place on a bf16 [4096, 16*128] tensor; cos/sin are fp32 [2048,128].
// Each thread owns a (d, d+64) pair -> no race.
// ---------------------------------------------------------------------------
__global__ __launch_bounds__(256) void rope_k(u16* __restrict__ t,
                                              const float* __restrict__ cs,
                                              const float* __restrict__ sn)
{
  const long idx = (long)blockIdx.x * 256 + threadIdx.x;   // 4096*1024 total
  const long m = idx >> 10;
  const int rest = (int)(idx & 1023);
  const int h = rest >> 6, d = rest & 63;
  const int s = (int)(m & 2047);
  const long base = m * 2048 + h * 128 + d;
  const float a  = bf2f(t[base]), b = bf2f(t[base + 64]);
  const float c1 = cs[s * 128 + d],      s1 = sn[s * 128 + d];
  const float c2 = cs[s * 128 + d + 64], s2 = sn[s * 128 + d + 64];
  t[base]      = f2bf(a * c1 - b * s1);
  t[base + 64] = f2bf(b * c2 + a * s2);
}

// ---------------------------------------------------------------------------
// Flash attention (causal). Block = 4 waves; wave w owns 16 q-rows.
// q,k: bf16 [b*2048+s, h*128+d] (post-RoPE). vt: bf16 [bh*128+d, s].
// K LDS layout blocked by dt=d/32: off_elts = dt*2048 + kj*32 + d%32
// VT LDS layout blocked by kt=kj/32: off_elts = ktb*4096 + d*32 + kj%32
// (64 B rows -> 2-way bank aliasing only, which is free)
// ---------------------------------------------------------------------------
__global__ __launch_bounds__(256) void attn_k(const u16* __restrict__ q,
                                              const u16* __restrict__ k,
                                              const u16* __restrict__ vt,
                                              u16* __restrict__ ao)
{
  __shared__ __align__(16) u16 Ks[64 * 128];     // 16 KB
  __shared__ __align__(16) u16 Vs[64 * 128];     // 16 KB
  __shared__ __align__(16) u16 Ps[4 * 16 * 72];  // per-wave P, padded stride 72
  const int qt = blockIdx.x, bh = blockIdx.y;
  const int b = bh >> 4, h = bh & 15;
  const int tid = threadIdx.x;
  const int w = tid >> 6, lane = tid & 63;
  const int ln = lane & 15, quad = lane >> 4;
  const int q0 = qt << 6;

  // Q fragments (A operand: m = ln, k = quad*8..+8 within each 32-chunk)
  bf8v aq[4];
  {
    const u16* qb = q + ((long)(b * 2048 + q0 + w * 16 + ln)) * 2048 + h * 128;
#pragma unroll
    for (int dt = 0; dt < 4; ++dt) aq[dt] = *(const bf8v*)(qb + dt * 32 + quad * 8);
  }
  f4v O[8] = {};
  float m_run[4] = {-1e30f, -1e30f, -1e30f, -1e30f};
  float l_run[4] = {0.f, 0.f, 0.f, 0.f};

  for (int kt = 0; kt <= qt; ++kt) {
    const int k0s = kt << 6;
    __syncthreads();   // previous tile fully consumed
#pragma unroll
    for (int it = 0; it < 4; ++it) {       // stage K tile (16 KB)
      const int c = it * 256 + tid;        // c = dt*256 + kj*4 + dd
      const int dt = c >> 8, kj = (c >> 2) & 63, dd = c & 3;
      const u16* g = k + ((long)(b * 2048 + k0s + kj)) * 2048 + h * 128 + dt * 32 + dd * 8;
      async16(g, (char*)Ks + it * 4096 + w * 1024);
    }
#pragma unroll
    for (int it = 0; it < 4; ++it) {       // stage VT tile (16 KB)
      const int c = it * 256 + tid;        // c = ktb*512 + d*4 + sub
      const int ktb = c >> 9, d = (c >> 2) & 127, sub = c & 3;
      const u16* g = vt + ((long)(bh * 128 + d)) * 2048 + k0s + ktb * 32 + sub * 8;
      async16(g, (char*)Vs + it * 4096 + w * 1024);
    }
    __syncthreads();

    // S = Q K^T  (D: row qi = quad*4+r, col kj = jt*16+ln)
    f4v S[4];
#pragma unroll
    for (int jt = 0; jt < 4; jt++) {
      f4v s = {};
#pragma unroll
      for (int dt = 0; dt < 4; dt++) {
        const bf8v bk = *(const bf8v*)&Ks[dt * 2048 + (jt * 16 + ln) * 32 + quad * 8];
        s = __builtin_amdgcn_mfma_f32_16x16x32_bf16(aq[dt], bk, s, 0, 0, 0);
      }
      S[jt] = s;
    }
    const float scl = 0.08838834764831845f;  // 1/sqrt(128)
    const int qi_base = q0 + w * 16 + quad * 4;
#pragma unroll
    for (int jt = 0; jt < 4; jt++) {
      const int kjg = k0s + jt * 16 + ln;
#pragma unroll
      for (int r = 0; r < 4; r++) {
        float v = S[jt][r] * scl;
        if (kjg > qi_base + r) v = -1e30f;   // causal mask
        S[jt][r] = v;
      }
    }
    // online softmax, per row r (16-lane butterflies stay inside the quad group)
#pragma unroll
    for (int r = 0; r < 4; r++) {
      float mx = fmaxf(fmaxf(S[0][r], S[1][r]), fmaxf(S[2][r], S[3][r]));
      mx = fmaxf(mx, __shfl_xor(mx, 1)); mx = fmaxf(mx, __shfl_xor(mx, 2));
      mx = fmaxf(mx, __shfl_xor(mx, 4)); mx = fmaxf(mx, __shfl_xor(mx, 8));
      const float mnew = fmaxf(m_run[r], mx);
      const float alpha = __expf(m_run[r] - mnew);
      m_run[r] = mnew;
      float ls = 0.f;
#pragma unroll
      for (int jt = 0; jt < 4; jt++) {
        const float p = __expf(S[jt][r] - mnew);
        S[jt][r] = p; ls += p;
      }
      ls += __shfl_xor(ls, 1); ls += __shfl_xor(ls, 2);
      ls += __shfl_xor(ls, 4); ls += __shfl_xor(ls, 8);
      l_run[r] = l_run[r] * alpha + ls;
#pragma unroll
      for (int nt = 0; nt < 8; nt++) O[nt][r] *= alpha;
    }
    // P round-trip through LDS: C-layout -> A-operand layout (m120 pattern)
    const int wbase = w * 16 * 72;
#pragma unroll
    for (int jt = 0; jt < 4; jt++)
#pragma unroll
      for (int r = 0; r < 4; r++)
        Ps[wbase + (quad * 4 + r) * 72 + jt * 16 + ln] = f2bf(S[jt][r]);
    __syncthreads();   // drains LDS writes (and keeps waves in step)
    bf8v ap[2];
#pragma unroll
    for (int ktb = 0; ktb < 2; ktb++)
      ap[ktb] = *(const bf8v*)&Ps[wbase + ln * 72 + ktb * 32 + quad * 8];
#pragma unroll
    for (int nt = 0; nt < 8; nt++) {
#pragma unroll
      for (int ktb = 0; ktb < 2; ktb++) {
        const bf8v bv = *(const bf8v*)&Vs[ktb * 4096 + (nt * 16 + ln) * 32 + quad * 8];
        O[nt] = __builtin_amdgcn_mfma_f32_16x16x32_bf16(ap[ktb], bv, O[nt], 0, 0, 0);
      }
    }
  }

  float inv[4];
#pragma unroll
  for (int r = 0; r < 4; r++) inv[r] = 1.0f / l_run[r];
  const long ob = ((long)(b * 2048 + q0 + w * 16 + quad * 4)) * 2048 + h * 128 + ln;
#pragma unroll
  for (int r = 0; r < 4; r++)
#pragma unroll
    for (int nt = 0; nt < 8; nt++)
      ao[ob + (long)r * 2048 + nt * 16] = f2bf(O[nt][r] * inv[r]);
}

// ---------------------------------------------------------------------------
extern "C" void kernel_launch(void* const* d_in, const int* in_sizes, int n_in,
                              void* d_out, int out_size, void* d_ws, size_t ws_size,
                              hipStream_t stream) {
  const float* x  = (const float*)d_in[0];
  const float* cs = (const float*)d_in[1];
  const float* sn = (const float*)d_in[2];
  const float* Wq = (const float*)d_in[3];
  const float* Wk = (const float*)d_in[4];
  const float* Wv = (const float*)d_in[5];
  const float* Wo = (const float*)d_in[6];
  float* out = (float*)d_out;

  // workspace (u16 units). aob aliases xb (x-bf16 dead after V GEMM).
  u16* xb  = (u16*)d_ws;            // [4096, 2048]   (16 MB)  | later: aob
  u16* wb  = xb + 8388608;          // [2048, 2048]   (8 MB, reused per-W)
  u16* qb  = wb + 4194304;          // [4096, 2048]   (16 MB)
  u16* kb  = qb + 8388608;          // [4096, 2048]   (16 MB)
  u16* vtb = kb + 8388608;          // [32, 128, 2048](16 MB)  V transposed
  u16* aob = xb;                    // alias

  const dim3 gg(NDIM / 128, MDIM / 128);   // (16, 32)

  f2b_k<<<8192, 256, 0, stream>>>(x, xb);
  f2b_k<<<4096, 256, 0, stream>>>(Wq, wb);
  gemm_bt<<<gg, 256, 0, stream>>>(xb, wb, qb, nullptr, 0);
  f2b_k<<<4096, 256, 0, stream>>>(Wk, wb);
  gemm_bt<<<gg, 256, 0, stream>>>(xb, wb, kb, nullptr, 0);
  f2b_k<<<4096, 256, 0, stream>>>(Wv, wb);
  gemm_bt<<<gg, 256, 0, stream>>>(xb, wb, vtb, nullptr, 1);
  rope_k<<<16384, 256, 0, stream>>>(qb, cs, sn);
  rope_k<<<16384, 256, 0, stream>>>(kb, cs, sn);
  attn_k<<<dim3(32, 32), 256, 0, stream>>>(qb, kb, vtb, aob);
  f2b_k<<<4096, 256, 0, stream>>>(Wo, wb);
  gemm_bt<<<gg, 256, 0, stream>>>(aob, wb, nullptr, out, 2);
}